// Round 9
// baseline (4152.621 us; speedup 1.0000x reference)
//
#include <hip/hip_runtime.h>
#include <math.h>

// Problem constants
#define B_   2048
#define T_   256
#define E_   124
#define V_   65
#define E2_  248
#define E3_  372
#define R_   4               // batch rows per block; packed-M rows 0-3=hi, 4-7=residual
#define NT_  512             // 8 waves
#define NB_  (B_ / R_)       // 512 blocks -> 2 per CU
#define NKC  4               // K chunks (124 padded to 128)
#define TCH  8               // timestep chunk for GX precompute

// ws offsets (unsigned shorts); frag block = 512 bf16 = 1KB — unchanged from R8
#define WS_WX  0                    // 24*4*512 = 49152
#define WS_WM2 49152
#define WS_HH  98304
#define WS_WM  147456               // 8*4*512
#define WS_HD  163840               // 5*4*512
#define WS_END 174080               // shorts = 348160 B

// LDS byte offsets (16B aligned)
#define HSTR 136    // row stride (shorts) for m/h/y/xe state rows
#define GXSTR 376   // GX row stride (shorts)
#define L_M1  0         // each state buf: 4*136*2 = 1088 B
#define L_M2  1088
#define L_HA1 2176
#define L_HA2 3264
#define L_HB1 4352
#define L_HB2 5440
#define L_Y1  6528
#define L_Y2  7616
#define L_ZR  8704      // 272 B zero row (A-operand rows 8-15)
#define L_GX  8976      // [8][4][376] shorts = 24064 -> ends 33040
#define L_XE  33040     // [2][8][4][136] shorts = 17408 -> ends 50448
#define L_BRZ 50448     // 248 f = 992
#define L_BIN 51440     // 124 f = 496
#define L_BHN 51936
#define L_BM  52432
#define L_WP  52928
#define L_LNG 53424
#define L_LNB 53920
#define L_BHD 54416     // 68 f = 272
#define L_P   54688     // 4 f
#define L_MU  54704
#define L_RS  54720
#define L_IDX 54736     // 4*256 int = 4096
#define SMEM_BYTES 58832

typedef __attribute__((ext_vector_type(8))) short short8v;
typedef __attribute__((ext_vector_type(4))) float float4v;

__device__ __forceinline__ unsigned short f2bf(float x) {
    unsigned u = __float_as_uint(x);
    unsigned r = (u + 0x7fffu + ((u >> 16) & 1u)) >> 16;
    return (unsigned short)r;
}
__device__ __forceinline__ float bf2f(unsigned short s) {
    return __uint_as_float(((unsigned)s) << 16);
}
__device__ __forceinline__ float sigmoid_f(float x) {
    return 1.0f / (1.0f + __expf(-x));
}
__device__ __forceinline__ float tanh_f(float x) {
    return 2.0f / (1.0f + __expf(-2.0f * x)) - 1.0f;
}

// identical to R8 (validated)
__global__ void prep_weights(const float* __restrict__ w_ih,
                             const float* __restrict__ w_hh,
                             const float* __restrict__ w_m,
                             const float* __restrict__ w_head,
                             unsigned short* __restrict__ ws) {
    for (int n = blockIdx.x * blockDim.x + threadIdx.x; n < WS_END;
         n += gridDim.x * blockDim.x) {
        const int r9 = n & 511;
        const int lane = r9 >> 3, j = r9 & 7;
        const int krel = (lane >> 4) * 8 + j;   // 0..31
        const int colrel = lane & 15;
        float w = 0.f;
        if (n < WS_WM2) {                       // WX: w_ih[:, 0:124]
            const int blk = n >> 9;
            const int c = blk & 3, tt = (blk >> 2) & 7, g = blk >> 5;
            const int k = c * 32 + krel, e = tt * 16 + colrel;
            if (k < E_ && e < E_) w = w_ih[(g * E_ + e) * E2_ + k];
        } else if (n < WS_HH) {                 // WM2: w_ih[:, 124:248]
            const int blk = (n - WS_WM2) >> 9;
            const int c = blk & 3, tt = (blk >> 2) & 7, g = blk >> 5;
            const int k = c * 32 + krel, e = tt * 16 + colrel;
            if (k < E_ && e < E_) w = w_ih[(g * E_ + e) * E2_ + E_ + k];
        } else if (n < WS_WM) {                 // HH: w_hh
            const int blk = (n - WS_HH) >> 9;
            const int c = blk & 3, tt = (blk >> 2) & 7, g = blk >> 5;
            const int k = c * 32 + krel, e = tt * 16 + colrel;
            if (k < E_ && e < E_) w = w_hh[(g * E_ + e) * E_ + k];
        } else if (n < WS_HD) {                 // WM: w_m (cand)
            const int blk = (n - WS_WM) >> 9;
            const int c = blk & 3, tt = blk >> 2;
            const int k = c * 32 + krel, e = tt * 16 + colrel;
            if (k < E_ && e < E_) w = w_m[e * E_ + k];
        } else {                                // HD: w_head
            const int blk = (n - WS_HD) >> 9;
            const int c = blk & 3, tt = blk >> 2;
            const int k = c * 32 + krel, v = tt * 16 + colrel;
            if (k < E_ && v < V_) w = w_head[v * E_ + k];
        }
        ws[n] = f2bf(w);
    }
}

__global__ void __launch_bounds__(NT_, 4)
gru_main(const int* __restrict__ idx, const float* __restrict__ tok,
         const float* __restrict__ pos,
         const float* __restrict__ b_ih, const float* __restrict__ b_hh,
         const float* __restrict__ w_p, const float* __restrict__ b_p,
         const float* __restrict__ b_m,
         const float* __restrict__ ln_g, const float* __restrict__ ln_b,
         const float* __restrict__ b_head,
         const unsigned short* __restrict__ ws, float* __restrict__ out) {
    extern __shared__ char smraw[];
    unsigned short* M1 = (unsigned short*)(smraw + L_M1);
    unsigned short* M2 = (unsigned short*)(smraw + L_M2);
    unsigned short* Y1 = (unsigned short*)(smraw + L_Y1);
    unsigned short* Y2 = (unsigned short*)(smraw + L_Y2);
    unsigned short* ZR = (unsigned short*)(smraw + L_ZR);
    unsigned short* GXs = (unsigned short*)(smraw + L_GX);
    unsigned short* XEs = (unsigned short*)(smraw + L_XE);
    float* BRZs = (float*)(smraw + L_BRZ);
    float* BINs = (float*)(smraw + L_BIN);
    float* BHNs = (float*)(smraw + L_BHN);
    float* BMs = (float*)(smraw + L_BM);
    float* WPs = (float*)(smraw + L_WP);
    float* LNGs = (float*)(smraw + L_LNG);
    float* LNBs = (float*)(smraw + L_LNB);
    float* BHDs = (float*)(smraw + L_BHD);
    float* Ps = (float*)(smraw + L_P);
    float* MUs = (float*)(smraw + L_MU);
    float* RSs = (float*)(smraw + L_RS);
    int* IDXs = (int*)(smraw + L_IDX);

    const int tid = threadIdx.x;
    const int lane = tid & 63;
    const int wv = tid >> 6;
    const int b0 = blockIdx.x * R_;
    const int frow = lane & 15;       // A row / C col
    const int fgrp = lane >> 4;       // k-group / C row-group
    const int eo = wv * 16 + frow;    // owned e (gate/cand column)
    const bool act = (fgrp < 2) && (eo < E_);   // gate-math lanes (2 rows each)

    // ---- one-time staging ----
    for (int i = tid; i < E2_; i += NT_) BRZs[i] = b_ih[i] + b_hh[i];
    for (int i = tid; i < E_; i += NT_) {
        BINs[i] = b_ih[E2_ + i];
        BHNs[i] = b_hh[E2_ + i];
        BMs[i] = b_m[i];
        WPs[i] = w_p[i];
        LNGs[i] = ln_g[i];
        LNBs[i] = ln_b[i];
    }
    for (int i = tid; i < V_; i += NT_) BHDs[i] = b_head[i];
    for (int i = tid; i < R_ * T_; i += NT_) IDXs[i] = idx[b0 * T_ + i];
    // zero state block (M1..Y2 + ZR contiguous: 8*544 + 136 = 4488 shorts)
    for (int i = tid; i < 4488; i += NT_) ((unsigned short*)smraw)[i] = 0;
    for (int i = tid; i < 2 * TCH * R_ * HSTR; i += NT_) XEs[i] = 0;
    const float bp = b_p[0];

    // ---- permanent register caches: 96 VGPR ----
    short8v hhf[3][NKC], wm2f[3][NKC];
#pragma unroll
    for (int g = 0; g < 3; ++g)
#pragma unroll
        for (int c = 0; c < NKC; ++c) {
            hhf[g][c]  = *(const short8v*)&ws[WS_HH  + ((g * 8 + wv) * NKC + c) * 512 + lane * 8];
            wm2f[g][c] = *(const short8v*)&ws[WS_WM2 + ((g * 8 + wv) * NKC + c) * 512 + lane * 8];
        }

    // per-lane packed-M source rows (frow 0-3 = hi, 4-7 = residual, 8-15 = zero)
    const unsigned short* Mrow = (frow < 4) ? M1 + frow * HSTR
                              : (frow < 8) ? M2 + (frow - 4) * HSTR : ZR;
    const unsigned short* Yrow = (frow < 4) ? Y1 + frow * HSTR
                              : (frow < 8) ? Y2 + (frow - 4) * HSTR : ZR;
    const unsigned short* Xrow = (frow < 4) ? XEs + frow * HSTR
                              : (frow < 8) ? XEs + TCH * R_ * HSTR + (frow - 4) * HSTR : ZR;
    const int xstep = (frow < 8) ? R_ * HSTR : 0;   // mt stride (0 for zero-row lanes)
    __syncthreads();

    float hnewv[2] = {0.f, 0.f};
    float candv[2] = {0.f, 0.f};

    for (int t = 0; t <= T_; ++t) {
        const int hw = t & 1;
        unsigned short* Hw1 = (unsigned short*)(smraw + (hw ? L_HB1 : L_HA1));
        unsigned short* Hw2 = (unsigned short*)(smraw + (hw ? L_HB2 : L_HA2));
        const unsigned short* Hr1 = (const unsigned short*)(smraw + (hw ? L_HA1 : L_HB1));
        const unsigned short* Hr2 = (const unsigned short*)(smraw + (hw ? L_HA2 : L_HB2));
        const unsigned short* Hrow = (frow < 4) ? Hr1 + frow * HSTR
                                  : (frow < 8) ? Hr2 + (frow - 4) * HSTR : ZR;
        const unsigned short* Hwrow = (frow < 4) ? (const unsigned short*)Hw1 + frow * HSTR
                                   : (frow < 8) ? (const unsigned short*)Hw2 + (frow - 4) * HSTR : ZR;

        // ===== chunk phase (every 8 steps): GX[t..t+7] = W_x @ x =====
        if (t < T_ && (t & 7) == 0) {
#pragma unroll
            for (int p = 0; p < 2; ++p) {
                const int i = tid + p * NT_;
                if (i < TCH * R_ * 31) {
                    const int mt = i / 124;
                    const int rem = i - mt * 124;
                    const int rr = rem / 31, q = rem - (rem / 31) * 31;
                    const int token = IDXs[rr * T_ + t + mt];
                    const int k = q * 4;
                    const float4 tv = *(const float4*)&tok[token * E_ + k];
                    const float4 pv = *(const float4*)&pos[(t + mt) * E_ + k];
#pragma unroll
                    for (int jj = 0; jj < 4; ++jj) {
                        const float x = ((const float*)&tv)[jj] + ((const float*)&pv)[jj];
                        const unsigned short x1 = f2bf(x);
                        XEs[((0 * TCH + mt) * R_ + rr) * HSTR + k + jj] = x1;
                        XEs[((1 * TCH + mt) * R_ + rr) * HSTR + k + jj] = f2bf(x - bf2f(x1));
                    }
                }
            }
            __syncthreads();
#pragma unroll
            for (int g = 0; g < 3; ++g) {
                short8v bx[NKC];
#pragma unroll
                for (int c = 0; c < NKC; ++c)
                    bx[c] = *(const short8v*)&ws[WS_WX + ((g * 8 + wv) * NKC + c) * 512 + lane * 8];
                for (int mt = 0; mt < TCH; ++mt) {
                    float4v ax = (float4v){0.f, 0.f, 0.f, 0.f};
#pragma unroll
                    for (int c = 0; c < NKC; ++c) {
                        const short8v a = *(const short8v*)&Xrow[mt * xstep + c * 32 + fgrp * 8];
                        ax = __builtin_amdgcn_mfma_f32_16x16x32_bf16(a, bx[c], ax, 0, 0, 0);
                    }
                    float axc[4];
#pragma unroll
                    for (int j = 0; j < 4; ++j) axc[j] = ax[j] + __shfl_xor(ax[j], 16);
                    if (act) {
#pragma unroll
                        for (int jj = 0; jj < 2; ++jj) {
                            const int j = fgrp * 2 + jj;   // batch row
                            GXs[(mt * R_ + j) * GXSTR + g * E_ + eo] = f2bf(axc[j]);
                        }
                    }
                }
            }
            // GX consumed lane-locally (each lane reads back exactly what it wrote)
        }

        // ===== phase A: gi_m/gh MFMAs + in-register gates =====
        if (t < T_) {
            short8v am[NKC], ah[NKC];
#pragma unroll
            for (int c = 0; c < NKC; ++c) {
                am[c] = *(const short8v*)&Mrow[c * 32 + fgrp * 8];
                ah[c] = *(const short8v*)&Hrow[c * 32 + fgrp * 8];
            }
            float4v accm[3], acch[3];
#pragma unroll
            for (int g = 0; g < 3; ++g) {
                accm[g] = (float4v){0.f, 0.f, 0.f, 0.f};
                acch[g] = (float4v){0.f, 0.f, 0.f, 0.f};
            }
#pragma unroll
            for (int g = 0; g < 3; ++g)
#pragma unroll
                for (int c = 0; c < NKC; ++c) {
                    accm[g] = __builtin_amdgcn_mfma_f32_16x16x32_bf16(am[c], wm2f[g][c], accm[g], 0, 0, 0);
                    acch[g] = __builtin_amdgcn_mfma_f32_16x16x32_bf16(ah[c], hhf[g][c], acch[g], 0, 0, 0);
                }

            // combine packed-M split rows (hi + residual); fgrp0/1 both get rows 0-3
            float gm[3][4], gh2[3][4];
#pragma unroll
            for (int g = 0; g < 3; ++g)
#pragma unroll
                for (int j = 0; j < 4; ++j) {
                    gm[g][j] = accm[g][j] + __shfl_xor(accm[g][j], 16);
                    gh2[g][j] = acch[g][j] + __shfl_xor(acch[g][j], 16);
                }
            // gates: fgrp0 -> rows 0,1 ; fgrp1 -> rows 2,3  (2 rows/lane)
            if (act) {
                const float brz0 = BRZs[eo], brz1 = BRZs[E_ + eo];
                const float bin = BINs[eo], bhn = BHNs[eo];
                const int gxbase = (t & 7) * R_ * GXSTR;
#pragma unroll
                for (int jj = 0; jj < 2; ++jj) {
                    const int j = fgrp * 2 + jj;   // reg index == batch row
                    const unsigned short* gxp = &GXs[gxbase + j * GXSTR];
                    const float rg = sigmoid_f(bf2f(gxp[eo]) + gm[0][j] + gh2[0][j] + brz0);
                    const float z = sigmoid_f(bf2f(gxp[E_ + eo]) + gm[1][j] + gh2[1][j] + brz1);
                    const float nn = tanh_f(bf2f(gxp[E2_ + eo]) + gm[2][j] + bin + rg * (gh2[2][j] + bhn));
                    const float hold = bf2f(Hr1[j * HSTR + eo]) + bf2f(Hr2[j * HSTR + eo]);
                    const float hv = (1.0f - z) * nn + z * hold;
                    hnewv[jj] = hv;
                    const unsigned short h1 = f2bf(hv);
                    Hw1[j * HSTR + eo] = h1;
                    Hw2[j * HSTR + eo] = f2bf(hv - bf2f(h1));
                }
            }
        }

        // ===== head logits for step t-1 (also runs at t == T_ epilogue) =====
        if (t > 0 && wv < 5) {
            float4v ahd = (float4v){0.f, 0.f, 0.f, 0.f};
#pragma unroll
            for (int c = 0; c < NKC; ++c) {
                const short8v ay = *(const short8v*)&Yrow[c * 32 + fgrp * 8];
                const short8v bh = *(const short8v*)&ws[WS_HD + (wv * NKC + c) * 512 + lane * 8];
                ahd = __builtin_amdgcn_mfma_f32_16x16x32_bf16(ay, bh, ahd, 0, 0, 0);
            }
            float hvl[4];
#pragma unroll
            for (int j = 0; j < 4; ++j) hvl[j] = ahd[j] + __shfl_xor(ahd[j], 16);
            if (fgrp < 2 && eo < V_) {
#pragma unroll
                for (int jj = 0; jj < 2; ++jj) {
                    const int j = fgrp * 2 + jj;   // batch row
                    __builtin_nontemporal_store(
                        hvl[j] + BHDs[eo],
                        &out[((size_t)(b0 + j) * T_ + (t - 1)) * V_ + eo]);
                }
            }
        }
        if (t == T_) break;
        __syncthreads();

        // ===== phase C: cand MFMA (w_m streamed) + p-dot + LN stats =====
        {
            float4v cc = (float4v){0.f, 0.f, 0.f, 0.f};
#pragma unroll
            for (int c = 0; c < NKC; ++c) {
                const short8v ahw = *(const short8v*)&Hwrow[c * 32 + fgrp * 8];
                const short8v bm = *(const short8v*)&ws[WS_WM + (wv * NKC + c) * 512 + lane * 8];
                cc = __builtin_amdgcn_mfma_f32_16x16x32_bf16(ahw, bm, cc, 0, 0, 0);
            }
            float cv[4];
#pragma unroll
            for (int j = 0; j < 4; ++j) cv[j] = cc[j] + __shfl_xor(cc[j], 16);
            candv[0] = cv[fgrp * 2 + 0];
            candv[1] = cv[(fgrp * 2 + 1) & 3];

            if (tid < 64) {                 // p-dot, rows 0-3 (wave 0)
                const int r = tid >> 4, g = tid & 15;
                float s = 0.f;
                for (int e = g; e < E_; e += 16)
                    s += (bf2f(Hw1[r * HSTR + e]) + bf2f(Hw2[r * HSTR + e])) * WPs[e];
                s += __shfl_xor(s, 1);
                s += __shfl_xor(s, 2);
                s += __shfl_xor(s, 4);
                s += __shfl_xor(s, 8);
                if (g == 0) Ps[r] = sigmoid_f(s + bp);
            } else if (tid < 128) {         // LN stats, rows 0-3 (wave 1)
                const int r = (tid - 64) >> 4, g = tid & 15;
                float s1 = 0.f, s2 = 0.f;
                for (int e = g; e < E_; e += 16) {
                    const float h = bf2f(Hw1[r * HSTR + e]) + bf2f(Hw2[r * HSTR + e]);
                    s1 += h;
                    s2 += h * h;
                }
                s1 += __shfl_xor(s1, 1);
                s1 += __shfl_xor(s1, 2);
                s1 += __shfl_xor(s1, 4);
                s1 += __shfl_xor(s1, 8);
                s2 += __shfl_xor(s2, 1);
                s2 += __shfl_xor(s2, 2);
                s2 += __shfl_xor(s2, 4);
                s2 += __shfl_xor(s2, 8);
                if (g == 0) {
                    const float mu = s1 * (1.0f / (float)E_);
                    const float var = s2 * (1.0f / (float)E_) - mu * mu;
                    MUs[r] = mu;
                    RSs[r] = rsqrtf(var + 1e-5f);
                }
            }
        }
        __syncthreads();

        // ===== phase D: m update + y = LN(h_new); 2 rows/lane =====
        if (act) {
            const float bm = BMs[eo], lng = LNGs[eo], lnb = LNBs[eo];
#pragma unroll
            for (int jj = 0; jj < 2; ++jj) {
                const int j = fgrp * 2 + jj;   // batch row
                const float pv = Ps[j];
                const float cand = tanh_f(candv[jj] + bm);
                const float mold = bf2f(M1[j * HSTR + eo]) + bf2f(M2[j * HSTR + eo]);
                const float mnew = (1.0f - pv) * mold + pv * cand;
                const unsigned short m1v = f2bf(mnew);
                M1[j * HSTR + eo] = m1v;
                M2[j * HSTR + eo] = f2bf(mnew - bf2f(m1v));
                const float yv = (hnewv[jj] - MUs[j]) * RSs[j] * lng + lnb;
                const unsigned short y1v = f2bf(yv);
                Y1[j * HSTR + eo] = y1v;
                Y2[j * HSTR + eo] = f2bf(yv - bf2f(y1v));
            }
        }
        __syncthreads();
    }
}

extern "C" void kernel_launch(void* const* d_in, const int* in_sizes, int n_in,
                              void* d_out, int out_size, void* d_ws, size_t ws_size,
                              hipStream_t stream) {
    const int* idx = (const int*)d_in[0];
    const float* tok = (const float*)d_in[1];
    const float* pos = (const float*)d_in[2];
    const float* w_ih = (const float*)d_in[3];
    const float* w_hh = (const float*)d_in[4];
    const float* b_ih = (const float*)d_in[5];
    const float* b_hh = (const float*)d_in[6];
    const float* w_p = (const float*)d_in[7];
    const float* b_p = (const float*)d_in[8];
    const float* w_m = (const float*)d_in[9];
    const float* b_m = (const float*)d_in[10];
    const float* ln_g = (const float*)d_in[11];
    const float* ln_b = (const float*)d_in[12];
    const float* w_head = (const float*)d_in[13];
    const float* b_head = (const float*)d_in[14];
    float* out = (float*)d_out;
    unsigned short* ws = (unsigned short*)d_ws;

    prep_weights<<<680, 256, 0, stream>>>(w_ih, w_hh, w_m, w_head, ws);

    (void)hipFuncSetAttribute((const void*)gru_main,
                              hipFuncAttributeMaxDynamicSharedMemorySize,
                              SMEM_BYTES);
    gru_main<<<NB_, NT_, SMEM_BYTES, stream>>>(idx, tok, pos, b_ih, b_hh, w_p, b_p,
                                               b_m, ln_g, ln_b, b_head, ws, out);
}

// Round 10
// 2099.863 us; speedup vs baseline: 1.9776x; 1.9776x over previous
//
#include <hip/hip_runtime.h>
#include <math.h>

// Problem constants
#define B_   2048
#define T_   256
#define E_   124
#define V_   65
#define E2_  248
#define E3_  372
#define R_   4               // batch rows per block; packed-M rows 0-3=hi, 4-7=residual
#define NT_  512             // 8 waves
#define NB_  (B_ / R_)       // 512 blocks -> 2 per CU
#define NKC  4               // K chunks (124 padded to 128)
#define TCH  8               // timestep chunk for GX precompute

// ws offsets (unsigned shorts); frag block = 512 bf16 = 1KB — unchanged from R8
#define WS_WX  0                    // 24*4*512 = 49152
#define WS_WM2 49152
#define WS_HH  98304
#define WS_WM  147456               // 8*4*512
#define WS_HD  163840               // 5*4*512
#define WS_END 174080               // shorts = 348160 B

// LDS byte offsets (16B aligned)
#define HSTR 136    // row stride (shorts) for m/h/y/xe state rows
#define GXSTR 376   // GX row stride (shorts)
#define L_M1  0         // each state buf: 4*136*2 = 1088 B
#define L_M2  1088
#define L_HA1 2176
#define L_HA2 3264
#define L_HB1 4352
#define L_HB2 5440
#define L_Y1  6528
#define L_Y2  7616
#define L_ZR  8704      // 272 B zero row (A-operand rows 8-15)
#define L_GX  8976      // [8][4][376] shorts = 24064 -> ends 33040
#define L_XE  33040     // [2][8][4][136] shorts = 17408 -> ends 50448
#define L_BRZ 50448     // 248 f = 992
#define L_BIN 51440     // 124 f = 496
#define L_BHN 51936
#define L_BM  52432
#define L_WP  52928
#define L_LNG 53424
#define L_LNB 53920
#define L_BHD 54416     // 68 f = 272
#define L_P   54688     // 4 f
#define L_MU  54704
#define L_RS  54720
#define L_IDX 54736     // 4*256 int = 4096
#define SMEM_BYTES 58832

typedef __attribute__((ext_vector_type(8))) short short8v;
typedef __attribute__((ext_vector_type(4))) float float4v;

__device__ __forceinline__ unsigned short f2bf(float x) {
    unsigned u = __float_as_uint(x);
    unsigned r = (u + 0x7fffu + ((u >> 16) & 1u)) >> 16;
    return (unsigned short)r;
}
__device__ __forceinline__ float bf2f(unsigned short s) {
    return __uint_as_float(((unsigned)s) << 16);
}
__device__ __forceinline__ float sigmoid_f(float x) {
    return 1.0f / (1.0f + __expf(-x));
}
__device__ __forceinline__ float tanh_f(float x) {
    return 2.0f / (1.0f + __expf(-2.0f * x)) - 1.0f;
}

// identical to R8/R9 (validated)
__global__ void prep_weights(const float* __restrict__ w_ih,
                             const float* __restrict__ w_hh,
                             const float* __restrict__ w_m,
                             const float* __restrict__ w_head,
                             unsigned short* __restrict__ ws) {
    for (int n = blockIdx.x * blockDim.x + threadIdx.x; n < WS_END;
         n += gridDim.x * blockDim.x) {
        const int r9 = n & 511;
        const int lane = r9 >> 3, j = r9 & 7;
        const int krel = (lane >> 4) * 8 + j;   // 0..31
        const int colrel = lane & 15;
        float w = 0.f;
        if (n < WS_WM2) {                       // WX: w_ih[:, 0:124]
            const int blk = n >> 9;
            const int c = blk & 3, tt = (blk >> 2) & 7, g = blk >> 5;
            const int k = c * 32 + krel, e = tt * 16 + colrel;
            if (k < E_ && e < E_) w = w_ih[(g * E_ + e) * E2_ + k];
        } else if (n < WS_HH) {                 // WM2: w_ih[:, 124:248]
            const int blk = (n - WS_WM2) >> 9;
            const int c = blk & 3, tt = (blk >> 2) & 7, g = blk >> 5;
            const int k = c * 32 + krel, e = tt * 16 + colrel;
            if (k < E_ && e < E_) w = w_ih[(g * E_ + e) * E2_ + E_ + k];
        } else if (n < WS_WM) {                 // HH: w_hh
            const int blk = (n - WS_HH) >> 9;
            const int c = blk & 3, tt = (blk >> 2) & 7, g = blk >> 5;
            const int k = c * 32 + krel, e = tt * 16 + colrel;
            if (k < E_ && e < E_) w = w_hh[(g * E_ + e) * E_ + k];
        } else if (n < WS_HD) {                 // WM: w_m (cand)
            const int blk = (n - WS_WM) >> 9;
            const int c = blk & 3, tt = blk >> 2;
            const int k = c * 32 + krel, e = tt * 16 + colrel;
            if (k < E_ && e < E_) w = w_m[e * E_ + k];
        } else {                                // HD: w_head
            const int blk = (n - WS_HD) >> 9;
            const int c = blk & 3, tt = blk >> 2;
            const int k = c * 32 + krel, v = tt * 16 + colrel;
            if (k < E_ && v < V_) w = w_head[v * E_ + k];
        }
        ws[n] = f2bf(w);
    }
}

__global__ void __launch_bounds__(NT_, 2)   // R9's (NT_,4) forced VGPR<=64 -> 11.5GB spill; 2 => 128 VGPR (R8-proven)
gru_main(const int* __restrict__ idx, const float* __restrict__ tok,
         const float* __restrict__ pos,
         const float* __restrict__ b_ih, const float* __restrict__ b_hh,
         const float* __restrict__ w_p, const float* __restrict__ b_p,
         const float* __restrict__ b_m,
         const float* __restrict__ ln_g, const float* __restrict__ ln_b,
         const float* __restrict__ b_head,
         const unsigned short* __restrict__ ws, float* __restrict__ out) {
    extern __shared__ char smraw[];
    unsigned short* M1 = (unsigned short*)(smraw + L_M1);
    unsigned short* M2 = (unsigned short*)(smraw + L_M2);
    unsigned short* Y1 = (unsigned short*)(smraw + L_Y1);
    unsigned short* Y2 = (unsigned short*)(smraw + L_Y2);
    unsigned short* ZR = (unsigned short*)(smraw + L_ZR);
    unsigned short* GXs = (unsigned short*)(smraw + L_GX);
    unsigned short* XEs = (unsigned short*)(smraw + L_XE);
    float* BRZs = (float*)(smraw + L_BRZ);
    float* BINs = (float*)(smraw + L_BIN);
    float* BHNs = (float*)(smraw + L_BHN);
    float* BMs = (float*)(smraw + L_BM);
    float* WPs = (float*)(smraw + L_WP);
    float* LNGs = (float*)(smraw + L_LNG);
    float* LNBs = (float*)(smraw + L_LNB);
    float* BHDs = (float*)(smraw + L_BHD);
    float* Ps = (float*)(smraw + L_P);
    float* MUs = (float*)(smraw + L_MU);
    float* RSs = (float*)(smraw + L_RS);
    int* IDXs = (int*)(smraw + L_IDX);

    const int tid = threadIdx.x;
    const int lane = tid & 63;
    const int wv = tid >> 6;
    const int b0 = blockIdx.x * R_;
    const int frow = lane & 15;       // A row / C col
    const int fgrp = lane >> 4;       // k-group / C row-group
    const int eo = wv * 16 + frow;    // owned e (gate/cand column)
    const bool act = (fgrp < 2) && (eo < E_);   // gate-math lanes (2 rows each)

    // ---- one-time staging ----
    for (int i = tid; i < E2_; i += NT_) BRZs[i] = b_ih[i] + b_hh[i];
    for (int i = tid; i < E_; i += NT_) {
        BINs[i] = b_ih[E2_ + i];
        BHNs[i] = b_hh[E2_ + i];
        BMs[i] = b_m[i];
        WPs[i] = w_p[i];
        LNGs[i] = ln_g[i];
        LNBs[i] = ln_b[i];
    }
    for (int i = tid; i < V_; i += NT_) BHDs[i] = b_head[i];
    for (int i = tid; i < R_ * T_; i += NT_) IDXs[i] = idx[b0 * T_ + i];
    // zero state block (M1..Y2 + ZR contiguous: 8*544 + 136 = 4488 shorts)
    for (int i = tid; i < 4488; i += NT_) ((unsigned short*)smraw)[i] = 0;
    for (int i = tid; i < 2 * TCH * R_ * HSTR; i += NT_) XEs[i] = 0;
    const float bp = b_p[0];

    // ---- permanent register caches: 96 VGPR ----
    short8v hhf[3][NKC], wm2f[3][NKC];
#pragma unroll
    for (int g = 0; g < 3; ++g)
#pragma unroll
        for (int c = 0; c < NKC; ++c) {
            hhf[g][c]  = *(const short8v*)&ws[WS_HH  + ((g * 8 + wv) * NKC + c) * 512 + lane * 8];
            wm2f[g][c] = *(const short8v*)&ws[WS_WM2 + ((g * 8 + wv) * NKC + c) * 512 + lane * 8];
        }

    // per-lane packed-M source rows (frow 0-3 = hi, 4-7 = residual, 8-15 = zero)
    const unsigned short* Mrow = (frow < 4) ? M1 + frow * HSTR
                              : (frow < 8) ? M2 + (frow - 4) * HSTR : ZR;
    const unsigned short* Yrow = (frow < 4) ? Y1 + frow * HSTR
                              : (frow < 8) ? Y2 + (frow - 4) * HSTR : ZR;
    const unsigned short* Xrow = (frow < 4) ? XEs + frow * HSTR
                              : (frow < 8) ? XEs + TCH * R_ * HSTR + (frow - 4) * HSTR : ZR;
    const int xstep = (frow < 8) ? R_ * HSTR : 0;   // mt stride (0 for zero-row lanes)
    __syncthreads();

    float hnewv[2] = {0.f, 0.f};
    float candv[2] = {0.f, 0.f};

    for (int t = 0; t <= T_; ++t) {
        const int hw = t & 1;
        unsigned short* Hw1 = (unsigned short*)(smraw + (hw ? L_HB1 : L_HA1));
        unsigned short* Hw2 = (unsigned short*)(smraw + (hw ? L_HB2 : L_HA2));
        const unsigned short* Hr1 = (const unsigned short*)(smraw + (hw ? L_HA1 : L_HB1));
        const unsigned short* Hr2 = (const unsigned short*)(smraw + (hw ? L_HA2 : L_HB2));
        const unsigned short* Hrow = (frow < 4) ? Hr1 + frow * HSTR
                                  : (frow < 8) ? Hr2 + (frow - 4) * HSTR : ZR;
        const unsigned short* Hwrow = (frow < 4) ? (const unsigned short*)Hw1 + frow * HSTR
                                   : (frow < 8) ? (const unsigned short*)Hw2 + (frow - 4) * HSTR : ZR;

        // ===== chunk phase (every 8 steps): GX[t..t+7] = W_x @ x =====
        if (t < T_ && (t & 7) == 0) {
#pragma unroll
            for (int p = 0; p < 2; ++p) {
                const int i = tid + p * NT_;
                if (i < TCH * R_ * 31) {
                    const int mt = i / 124;
                    const int rem = i - mt * 124;
                    const int rr = rem / 31, q = rem - (rem / 31) * 31;
                    const int token = IDXs[rr * T_ + t + mt];
                    const int k = q * 4;
                    const float4 tv = *(const float4*)&tok[token * E_ + k];
                    const float4 pv = *(const float4*)&pos[(t + mt) * E_ + k];
#pragma unroll
                    for (int jj = 0; jj < 4; ++jj) {
                        const float x = ((const float*)&tv)[jj] + ((const float*)&pv)[jj];
                        const unsigned short x1 = f2bf(x);
                        XEs[((0 * TCH + mt) * R_ + rr) * HSTR + k + jj] = x1;
                        XEs[((1 * TCH + mt) * R_ + rr) * HSTR + k + jj] = f2bf(x - bf2f(x1));
                    }
                }
            }
            __syncthreads();
#pragma unroll
            for (int g = 0; g < 3; ++g) {
                short8v bx[NKC];
#pragma unroll
                for (int c = 0; c < NKC; ++c)
                    bx[c] = *(const short8v*)&ws[WS_WX + ((g * 8 + wv) * NKC + c) * 512 + lane * 8];
                for (int mt = 0; mt < TCH; ++mt) {
                    float4v ax = (float4v){0.f, 0.f, 0.f, 0.f};
#pragma unroll
                    for (int c = 0; c < NKC; ++c) {
                        const short8v a = *(const short8v*)&Xrow[mt * xstep + c * 32 + fgrp * 8];
                        ax = __builtin_amdgcn_mfma_f32_16x16x32_bf16(a, bx[c], ax, 0, 0, 0);
                    }
                    float axc[4];
#pragma unroll
                    for (int j = 0; j < 4; ++j) axc[j] = ax[j] + __shfl_xor(ax[j], 16);
                    if (act) {
#pragma unroll
                        for (int jj = 0; jj < 2; ++jj) {
                            const int j = fgrp * 2 + jj;   // batch row
                            GXs[(mt * R_ + j) * GXSTR + g * E_ + eo] = f2bf(axc[j]);
                        }
                    }
                }
            }
            // GX consumed lane-locally (each lane reads back exactly what it wrote)
        }

        // ===== phase A: gi_m/gh MFMAs + in-register gates =====
        if (t < T_) {
            short8v am[NKC], ah[NKC];
#pragma unroll
            for (int c = 0; c < NKC; ++c) {
                am[c] = *(const short8v*)&Mrow[c * 32 + fgrp * 8];
                ah[c] = *(const short8v*)&Hrow[c * 32 + fgrp * 8];
            }
            float4v accm[3], acch[3];
#pragma unroll
            for (int g = 0; g < 3; ++g) {
                accm[g] = (float4v){0.f, 0.f, 0.f, 0.f};
                acch[g] = (float4v){0.f, 0.f, 0.f, 0.f};
            }
#pragma unroll
            for (int g = 0; g < 3; ++g)
#pragma unroll
                for (int c = 0; c < NKC; ++c) {
                    accm[g] = __builtin_amdgcn_mfma_f32_16x16x32_bf16(am[c], wm2f[g][c], accm[g], 0, 0, 0);
                    acch[g] = __builtin_amdgcn_mfma_f32_16x16x32_bf16(ah[c], hhf[g][c], acch[g], 0, 0, 0);
                }

            // combine packed-M split rows (hi + residual); fgrp0/1 both get rows 0-3
            float gm[3][4], gh2[3][4];
#pragma unroll
            for (int g = 0; g < 3; ++g)
#pragma unroll
                for (int j = 0; j < 4; ++j) {
                    gm[g][j] = accm[g][j] + __shfl_xor(accm[g][j], 16);
                    gh2[g][j] = acch[g][j] + __shfl_xor(acch[g][j], 16);
                }
            // gates: fgrp0 -> rows 0,1 ; fgrp1 -> rows 2,3  (2 rows/lane)
            if (act) {
                const float brz0 = BRZs[eo], brz1 = BRZs[E_ + eo];
                const float bin = BINs[eo], bhn = BHNs[eo];
                const int gxbase = (t & 7) * R_ * GXSTR;
#pragma unroll
                for (int jj = 0; jj < 2; ++jj) {
                    const int j = fgrp * 2 + jj;   // reg index == batch row
                    const unsigned short* gxp = &GXs[gxbase + j * GXSTR];
                    const float rg = sigmoid_f(bf2f(gxp[eo]) + gm[0][j] + gh2[0][j] + brz0);
                    const float z = sigmoid_f(bf2f(gxp[E_ + eo]) + gm[1][j] + gh2[1][j] + brz1);
                    const float nn = tanh_f(bf2f(gxp[E2_ + eo]) + gm[2][j] + bin + rg * (gh2[2][j] + bhn));
                    const float hold = bf2f(Hr1[j * HSTR + eo]) + bf2f(Hr2[j * HSTR + eo]);
                    const float hv = (1.0f - z) * nn + z * hold;
                    hnewv[jj] = hv;
                    const unsigned short h1 = f2bf(hv);
                    Hw1[j * HSTR + eo] = h1;
                    Hw2[j * HSTR + eo] = f2bf(hv - bf2f(h1));
                }
            }
        }

        // ===== head logits for step t-1 (also runs at t == T_ epilogue) =====
        if (t > 0 && wv < 5) {
            float4v ahd = (float4v){0.f, 0.f, 0.f, 0.f};
#pragma unroll
            for (int c = 0; c < NKC; ++c) {
                const short8v ay = *(const short8v*)&Yrow[c * 32 + fgrp * 8];
                const short8v bh = *(const short8v*)&ws[WS_HD + (wv * NKC + c) * 512 + lane * 8];
                ahd = __builtin_amdgcn_mfma_f32_16x16x32_bf16(ay, bh, ahd, 0, 0, 0);
            }
            float hvl[4];
#pragma unroll
            for (int j = 0; j < 4; ++j) hvl[j] = ahd[j] + __shfl_xor(ahd[j], 16);
            if (fgrp < 2 && eo < V_) {
#pragma unroll
                for (int jj = 0; jj < 2; ++jj) {
                    const int j = fgrp * 2 + jj;   // batch row
                    __builtin_nontemporal_store(
                        hvl[j] + BHDs[eo],
                        &out[((size_t)(b0 + j) * T_ + (t - 1)) * V_ + eo]);
                }
            }
        }
        if (t == T_) break;
        __syncthreads();

        // ===== phase C: cand MFMA (w_m streamed) + p-dot + LN stats =====
        {
            float4v cc = (float4v){0.f, 0.f, 0.f, 0.f};
#pragma unroll
            for (int c = 0; c < NKC; ++c) {
                const short8v ahw = *(const short8v*)&Hwrow[c * 32 + fgrp * 8];
                const short8v bm = *(const short8v*)&ws[WS_WM + (wv * NKC + c) * 512 + lane * 8];
                cc = __builtin_amdgcn_mfma_f32_16x16x32_bf16(ahw, bm, cc, 0, 0, 0);
            }
            float cv[4];
#pragma unroll
            for (int j = 0; j < 4; ++j) cv[j] = cc[j] + __shfl_xor(cc[j], 16);
            candv[0] = cv[fgrp * 2 + 0];
            candv[1] = cv[(fgrp * 2 + 1) & 3];

            if (tid < 64) {                 // p-dot, rows 0-3 (wave 0)
                const int r = tid >> 4, g = tid & 15;
                float s = 0.f;
                for (int e = g; e < E_; e += 16)
                    s += (bf2f(Hw1[r * HSTR + e]) + bf2f(Hw2[r * HSTR + e])) * WPs[e];
                s += __shfl_xor(s, 1);
                s += __shfl_xor(s, 2);
                s += __shfl_xor(s, 4);
                s += __shfl_xor(s, 8);
                if (g == 0) Ps[r] = sigmoid_f(s + bp);
            } else if (tid < 128) {         // LN stats, rows 0-3 (wave 1)
                const int r = (tid - 64) >> 4, g = tid & 15;
                float s1 = 0.f, s2 = 0.f;
                for (int e = g; e < E_; e += 16) {
                    const float h = bf2f(Hw1[r * HSTR + e]) + bf2f(Hw2[r * HSTR + e]);
                    s1 += h;
                    s2 += h * h;
                }
                s1 += __shfl_xor(s1, 1);
                s1 += __shfl_xor(s1, 2);
                s1 += __shfl_xor(s1, 4);
                s1 += __shfl_xor(s1, 8);
                s2 += __shfl_xor(s2, 1);
                s2 += __shfl_xor(s2, 2);
                s2 += __shfl_xor(s2, 4);
                s2 += __shfl_xor(s2, 8);
                if (g == 0) {
                    const float mu = s1 * (1.0f / (float)E_);
                    const float var = s2 * (1.0f / (float)E_) - mu * mu;
                    MUs[r] = mu;
                    RSs[r] = rsqrtf(var + 1e-5f);
                }
            }
        }
        __syncthreads();

        // ===== phase D: m update + y = LN(h_new); 2 rows/lane =====
        if (act) {
            const float bm = BMs[eo], lng = LNGs[eo], lnb = LNBs[eo];
#pragma unroll
            for (int jj = 0; jj < 2; ++jj) {
                const int j = fgrp * 2 + jj;   // batch row
                const float pv = Ps[j];
                const float cand = tanh_f(candv[jj] + bm);
                const float mold = bf2f(M1[j * HSTR + eo]) + bf2f(M2[j * HSTR + eo]);
                const float mnew = (1.0f - pv) * mold + pv * cand;
                const unsigned short m1v = f2bf(mnew);
                M1[j * HSTR + eo] = m1v;
                M2[j * HSTR + eo] = f2bf(mnew - bf2f(m1v));
                const float yv = (hnewv[jj] - MUs[j]) * RSs[j] * lng + lnb;
                const unsigned short y1v = f2bf(yv);
                Y1[j * HSTR + eo] = y1v;
                Y2[j * HSTR + eo] = f2bf(yv - bf2f(y1v));
            }
        }
        __syncthreads();
    }
}

extern "C" void kernel_launch(void* const* d_in, const int* in_sizes, int n_in,
                              void* d_out, int out_size, void* d_ws, size_t ws_size,
                              hipStream_t stream) {
    const int* idx = (const int*)d_in[0];
    const float* tok = (const float*)d_in[1];
    const float* pos = (const float*)d_in[2];
    const float* w_ih = (const float*)d_in[3];
    const float* w_hh = (const float*)d_in[4];
    const float* b_ih = (const float*)d_in[5];
    const float* b_hh = (const float*)d_in[6];
    const float* w_p = (const float*)d_in[7];
    const float* b_p = (const float*)d_in[8];
    const float* w_m = (const float*)d_in[9];
    const float* b_m = (const float*)d_in[10];
    const float* ln_g = (const float*)d_in[11];
    const float* ln_b = (const float*)d_in[12];
    const float* w_head = (const float*)d_in[13];
    const float* b_head = (const float*)d_in[14];
    float* out = (float*)d_out;
    unsigned short* ws = (unsigned short*)d_ws;

    prep_weights<<<680, 256, 0, stream>>>(w_ih, w_hh, w_m, w_head, ws);

    (void)hipFuncSetAttribute((const void*)gru_main,
                              hipFuncAttributeMaxDynamicSharedMemorySize,
                              SMEM_BYTES);
    gru_main<<<NB_, NT_, SMEM_BYTES, stream>>>(idx, tok, pos, b_ih, b_hh, w_p, b_p,
                                               b_m, ln_g, ln_b, b_head, ws, out);
}

// Round 13
// 1200.123 us; speedup vs baseline: 3.4602x; 1.7497x over previous
//
#include <hip/hip_runtime.h>
#include <math.h>

// Problem constants
#define B_   2048
#define T_   256
#define E_   124
#define V_   65
#define E2_  248
#define E3_  372
#define R_   8               // batch rows per block; packed-M rows 0-7=hi, 8-15=residual
#define NT_  512             // 8 waves
#define NB_  (B_ / R_)       // 256 blocks -> 1 per CU
#define NKC  4               // K chunks (124 padded to 128)
#define TCH  8               // timestep chunk for GX precompute

// ws offsets (unsigned shorts); frag block = 512 bf16 = 1KB
// gate-major tiling for WX/WM2/HH: block id = ((g*8 + tt)*4 + c)
//   holds W[col = g*124 + tt*16 + (lane&15)][k = c*32 + (lane>>4)*8 + j]
// HD holds W' = ln_g ∘ w_head (LN folded into head weights)
#define WS_WX  0                    // 24*4*512 = 49152
#define WS_WM2 49152
#define WS_HH  98304
#define WS_WM  147456               // 8*4*512
#define WS_HD  163840               // 5*4*512
#define WS_END 174080               // shorts = 348160 B

// LDS byte offsets (16B aligned)
#define HSTR 136    // row stride (shorts) for m/h/xe state rows
#define GXSTR 376   // GX row stride (shorts)
#define L_M1  0         // each state buf: 8*136*2 = 2176 B
#define L_M2  2176
#define L_HA1 4352
#define L_HA2 6528
#define L_HB1 8704
#define L_HB2 10880     // state block ends 13056
#define L_GX  13056     // [8][8][376] shorts = 48128 -> ends 61184
#define L_XE  61184     // [2][8][8][136] shorts = 34816 -> ends 96000
#define L_BRZ 96000     // 248 f
#define L_BIN 96992     // 124 f
#define L_BHN 97488
#define L_BM  97984
#define L_WP  98480
#define L_C1  98976     // 68 f : c1[v] = sum_e ln_g[e]*w_head[v][e]
#define L_C2B 99248     // 68 f : c2[v] = sum_e ln_b[e]*w_head[v][e] + b_head[v]
#define L_P   99520     // 8 f
#define L_MU  99552
#define L_RS  99584
#define L_IDX 99616     // 8*256 int = 8192
#define SMEM_BYTES 107808

typedef __attribute__((ext_vector_type(8))) short short8v;
typedef __attribute__((ext_vector_type(4))) float float4v;

__device__ __forceinline__ unsigned short f2bf(float x) {
    unsigned u = __float_as_uint(x);
    unsigned r = (u + 0x7fffu + ((u >> 16) & 1u)) >> 16;
    return (unsigned short)r;
}
__device__ __forceinline__ float bf2f(unsigned short s) {
    return __uint_as_float(((unsigned)s) << 16);
}
__device__ __forceinline__ float sigmoid_f(float x) {
    return 1.0f / (1.0f + __expf(-x));
}
__device__ __forceinline__ float tanh_f(float x) {
    return 2.0f / (1.0f + __expf(-2.0f * x)) - 1.0f;
}

__global__ void prep_weights(const float* __restrict__ w_ih,
                             const float* __restrict__ w_hh,
                             const float* __restrict__ w_m,
                             const float* __restrict__ w_head,
                             const float* __restrict__ ln_g,
                             unsigned short* __restrict__ ws) {
    for (int n = blockIdx.x * blockDim.x + threadIdx.x; n < WS_END;
         n += gridDim.x * blockDim.x) {
        const int r9 = n & 511;
        const int lane = r9 >> 3, j = r9 & 7;
        const int krel = (lane >> 4) * 8 + j;   // 0..31
        const int colrel = lane & 15;
        float w = 0.f;
        if (n < WS_WM2) {                       // WX: w_ih[:, 0:124]
            const int blk = n >> 9;
            const int c = blk & 3, tt = (blk >> 2) & 7, g = blk >> 5;
            const int k = c * 32 + krel, e = tt * 16 + colrel;
            if (k < E_ && e < E_) w = w_ih[(g * E_ + e) * E2_ + k];
        } else if (n < WS_HH) {                 // WM2: w_ih[:, 124:248]
            const int blk = (n - WS_WM2) >> 9;
            const int c = blk & 3, tt = (blk >> 2) & 7, g = blk >> 5;
            const int k = c * 32 + krel, e = tt * 16 + colrel;
            if (k < E_ && e < E_) w = w_ih[(g * E_ + e) * E2_ + E_ + k];
        } else if (n < WS_WM) {                 // HH: w_hh
            const int blk = (n - WS_HH) >> 9;
            const int c = blk & 3, tt = (blk >> 2) & 7, g = blk >> 5;
            const int k = c * 32 + krel, e = tt * 16 + colrel;
            if (k < E_ && e < E_) w = w_hh[(g * E_ + e) * E_ + k];
        } else if (n < WS_HD) {                 // WM: w_m (cand)
            const int blk = (n - WS_WM) >> 9;
            const int c = blk & 3, tt = blk >> 2;
            const int k = c * 32 + krel, e = tt * 16 + colrel;
            if (k < E_ && e < E_) w = w_m[e * E_ + k];
        } else {                                // HD: W' = ln_g ∘ w_head
            const int blk = (n - WS_HD) >> 9;
            const int c = blk & 3, tt = blk >> 2;
            const int k = c * 32 + krel, v = tt * 16 + colrel;
            if (k < E_ && v < V_) w = w_head[v * E_ + k] * ln_g[k];
        }
        ws[n] = f2bf(w);
    }
}

__global__ void __launch_bounds__(NT_, 2)
gru_main(const int* __restrict__ idx, const float* __restrict__ tok,
         const float* __restrict__ pos,
         const float* __restrict__ b_ih, const float* __restrict__ b_hh,
         const float* __restrict__ w_p, const float* __restrict__ b_p,
         const float* __restrict__ b_m,
         const float* __restrict__ ln_g, const float* __restrict__ ln_b,
         const float* __restrict__ w_head, const float* __restrict__ b_head,
         const unsigned short* __restrict__ ws, float* __restrict__ out) {
    extern __shared__ char smraw[];
    unsigned short* M1 = (unsigned short*)(smraw + L_M1);
    unsigned short* M2 = (unsigned short*)(smraw + L_M2);
    unsigned short* GXs = (unsigned short*)(smraw + L_GX);
    unsigned short* XEs = (unsigned short*)(smraw + L_XE);
    float* BRZs = (float*)(smraw + L_BRZ);
    float* BINs = (float*)(smraw + L_BIN);
    float* BHNs = (float*)(smraw + L_BHN);
    float* BMs = (float*)(smraw + L_BM);
    float* WPs = (float*)(smraw + L_WP);
    float* C1s = (float*)(smraw + L_C1);
    float* C2Bs = (float*)(smraw + L_C2B);
    float* Ps = (float*)(smraw + L_P);
    float* MUs = (float*)(smraw + L_MU);
    float* RSs = (float*)(smraw + L_RS);
    int* IDXs = (int*)(smraw + L_IDX);

    const int tid = threadIdx.x;
    const int lane = tid & 63;
    const int wv = tid >> 6;
    const int b0 = blockIdx.x * R_;
    const int frow = lane & 15;       // A row / C col
    const int fgrp = lane >> 4;       // k-group / C row-group
    const int eo = wv * 16 + frow;    // owned e (gate/cand column)
    const bool act = (fgrp < 2) && (eo < E_);
    const bool hdw = (wv >= 2) && (wv < 7);   // head waves
    const int vo = (wv - 2) * 16 + frow;      // head output col

    // ---- one-time staging ----
    for (int i = tid; i < E2_; i += NT_) BRZs[i] = b_ih[i] + b_hh[i];
    for (int i = tid; i < E_; i += NT_) {
        BINs[i] = b_ih[E2_ + i];
        BHNs[i] = b_hh[E2_ + i];
        BMs[i] = b_m[i];
        WPs[i] = w_p[i];
    }
    for (int v = tid; v < V_; v += NT_) {       // LN-fold constants
        float s1 = 0.f, s2 = 0.f;
        for (int e = 0; e < E_; ++e) {
            const float w = w_head[v * E_ + e];
            s1 += ln_g[e] * w;
            s2 += ln_b[e] * w;
        }
        C1s[v] = s1;
        C2Bs[v] = s2 + b_head[v];
    }
    for (int i = tid; i < R_ * T_; i += NT_) IDXs[i] = idx[b0 * T_ + i];
    // zero state block (M1..HB2 contiguous: 6 buffers * 1088 shorts)
    for (int i = tid; i < 6528; i += NT_) ((unsigned short*)smraw)[i] = 0;
    for (int i = tid; i < 2 * TCH * R_ * HSTR; i += NT_) XEs[i] = 0;
    const float bp = b_p[0];

    // ---- permanent register caches: 96 VGPR (R8-proven) ----
    short8v hhf[3][NKC], wm2f[3][NKC];
#pragma unroll
    for (int g = 0; g < 3; ++g)
#pragma unroll
        for (int c = 0; c < NKC; ++c) {
            hhf[g][c]  = *(const short8v*)&ws[WS_HH  + ((g * 8 + wv) * NKC + c) * 512 + lane * 8];
            wm2f[g][c] = *(const short8v*)&ws[WS_WM2 + ((g * 8 + wv) * NKC + c) * 512 + lane * 8];
        }

    // per-lane packed-M source rows (frow 0-7 = hi part, 8-15 = residual)
    const unsigned short* Mrow = (frow < 8 ? M1 : M2) + (frow & 7) * HSTR;
    const unsigned short* Xrow = XEs + (frow < 8 ? 0 : 1) * (TCH * R_ * HSTR) + (frow & 7) * HSTR;
    __syncthreads();

    float hnewv[4] = {0.f, 0.f, 0.f, 0.f};
    float candv[4] = {0.f, 0.f, 0.f, 0.f};
    float hdv[4] = {0.f, 0.f, 0.f, 0.f};

    for (int t = 0; t < T_; ++t) {
        const int hw = t & 1;
        unsigned short* Hw1 = (unsigned short*)(smraw + (hw ? L_HB1 : L_HA1));
        unsigned short* Hw2 = (unsigned short*)(smraw + (hw ? L_HB2 : L_HA2));
        const unsigned short* Hr1 = (const unsigned short*)(smraw + (hw ? L_HA1 : L_HB1));
        const unsigned short* Hr2 = (const unsigned short*)(smraw + (hw ? L_HA2 : L_HB2));
        const unsigned short* Hrow = (frow < 8 ? Hr1 : Hr2) + (frow & 7) * HSTR;
        const unsigned short* Hwrow = (frow < 8 ? (const unsigned short*)Hw1
                                                : (const unsigned short*)Hw2) + (frow & 7) * HSTR;

        // ===== chunk phase (every 8 steps): GX[t..t+7] = W_x @ x =====
        if ((t & 7) == 0) {
#pragma unroll
            for (int p = 0; p < 4; ++p) {
                const int i = tid + p * NT_;
                if (i < TCH * R_ * 31) {
                    const int mt = i / 248;
                    const int rem = i - mt * 248;
                    const int rr = rem / 31, q = rem - (rem / 31) * 31;
                    const int token = IDXs[rr * T_ + t + mt];
                    const int k = q * 4;
                    const float4 tv = *(const float4*)&tok[token * E_ + k];
                    const float4 pv = *(const float4*)&pos[(t + mt) * E_ + k];
#pragma unroll
                    for (int jj = 0; jj < 4; ++jj) {
                        const float x = ((const float*)&tv)[jj] + ((const float*)&pv)[jj];
                        const unsigned short x1 = f2bf(x);
                        XEs[((0 * TCH + mt) * R_ + rr) * HSTR + k + jj] = x1;
                        XEs[((1 * TCH + mt) * R_ + rr) * HSTR + k + jj] = f2bf(x - bf2f(x1));
                    }
                }
            }
            __syncthreads();
#pragma unroll
            for (int g = 0; g < 3; ++g) {
                short8v bx[NKC];
#pragma unroll
                for (int c = 0; c < NKC; ++c)
                    bx[c] = *(const short8v*)&ws[WS_WX + ((g * 8 + wv) * NKC + c) * 512 + lane * 8];
                for (int mt = 0; mt < TCH; ++mt) {
                    float4v ax = (float4v){0.f, 0.f, 0.f, 0.f};
#pragma unroll
                    for (int c = 0; c < NKC; ++c) {
                        const short8v a = *(const short8v*)&Xrow[mt * R_ * HSTR + c * 32 + fgrp * 8];
                        ax = __builtin_amdgcn_mfma_f32_16x16x32_bf16(a, bx[c], ax, 0, 0, 0);
                    }
#pragma unroll
                    for (int j = 0; j < 4; ++j) {
                        const float v = ax[j] + __shfl_xor(ax[j], 32);
                        if (act) GXs[(mt * R_ + fgrp * 4 + j) * GXSTR + g * E_ + eo] = f2bf(v);
                    }
                }
            }
            // GX consumed lane-locally (same lane wrote its own gate entries)
        }

        // ===== phase A: gi_m/gh MFMAs + in-register gates -> h_new =====
        {
            short8v am[NKC], ah[NKC];
#pragma unroll
            for (int c = 0; c < NKC; ++c) {
                am[c] = *(const short8v*)&Mrow[c * 32 + fgrp * 8];
                ah[c] = *(const short8v*)&Hrow[c * 32 + fgrp * 8];
            }
            float4v accm[3], acch[3];
#pragma unroll
            for (int g = 0; g < 3; ++g) {
                accm[g] = (float4v){0.f, 0.f, 0.f, 0.f};
                acch[g] = (float4v){0.f, 0.f, 0.f, 0.f};
            }
#pragma unroll
            for (int g = 0; g < 3; ++g)
#pragma unroll
                for (int c = 0; c < NKC; ++c) {
                    accm[g] = __builtin_amdgcn_mfma_f32_16x16x32_bf16(am[c], wm2f[g][c], accm[g], 0, 0, 0);
                    acch[g] = __builtin_amdgcn_mfma_f32_16x16x32_bf16(ah[c], hhf[g][c], acch[g], 0, 0, 0);
                }
            float gm[3][4], gh2[3][4];
#pragma unroll
            for (int g = 0; g < 3; ++g)
#pragma unroll
                for (int j = 0; j < 4; ++j) {
                    gm[g][j] = accm[g][j] + __shfl_xor(accm[g][j], 32);
                    gh2[g][j] = acch[g][j] + __shfl_xor(acch[g][j], 32);
                }
            if (act) {
                const float brz0 = BRZs[eo], brz1 = BRZs[E_ + eo];
                const float bin = BINs[eo], bhn = BHNs[eo];
                const int gxbase = ((t & 7) * R_ + fgrp * 4) * GXSTR;
#pragma unroll
                for (int j = 0; j < 4; ++j) {
                    const int r = fgrp * 4 + j;
                    const unsigned short* gxp = &GXs[gxbase + j * GXSTR];
                    const float rg = sigmoid_f(bf2f(gxp[eo]) + gm[0][j] + gh2[0][j] + brz0);
                    const float z = sigmoid_f(bf2f(gxp[E_ + eo]) + gm[1][j] + gh2[1][j] + brz1);
                    const float nn = tanh_f(bf2f(gxp[E2_ + eo]) + gm[2][j] + bin + rg * (gh2[2][j] + bhn));
                    const float hold = bf2f(Hr1[r * HSTR + eo]) + bf2f(Hr2[r * HSTR + eo]);
                    const float hv = (1.0f - z) * nn + z * hold;
                    hnewv[j] = hv;
                    const unsigned short h1 = f2bf(hv);
                    Hw1[r * HSTR + eo] = h1;
                    Hw2[r * HSTR + eo] = f2bf(hv - bf2f(h1));
                }
            }
        }
        __syncthreads();

        // ===== phase C: cand MFMA (all) + head MFMA on h (wv2-6) + p/LN (wv0-1) =====
        {
            short8v ahw[NKC];
#pragma unroll
            for (int c = 0; c < NKC; ++c)
                ahw[c] = *(const short8v*)&Hwrow[c * 32 + fgrp * 8];
            float4v cc = (float4v){0.f, 0.f, 0.f, 0.f};
#pragma unroll
            for (int c = 0; c < NKC; ++c) {
                const short8v bm = *(const short8v*)&ws[WS_WM + (wv * NKC + c) * 512 + lane * 8];
                cc = __builtin_amdgcn_mfma_f32_16x16x32_bf16(ahw[c], bm, cc, 0, 0, 0);
            }
#pragma unroll
            for (int j = 0; j < 4; ++j) candv[j] = cc[j] + __shfl_xor(cc[j], 32);

            if (hdw) {   // head on h_t with LN-folded weights W'
                float4v ad = (float4v){0.f, 0.f, 0.f, 0.f};
#pragma unroll
                for (int c = 0; c < NKC; ++c) {
                    const short8v bh = *(const short8v*)&ws[WS_HD + ((wv - 2) * NKC + c) * 512 + lane * 8];
                    ad = __builtin_amdgcn_mfma_f32_16x16x32_bf16(ahw[c], bh, ad, 0, 0, 0);
                }
#pragma unroll
                for (int j = 0; j < 4; ++j) hdv[j] = ad[j] + __shfl_xor(ad[j], 32);
            }

            if (tid < 128) {   // merged p-dot + LN stats (rows 0-7, 16 lanes each)
                const int r = tid >> 4, g = tid & 15;
                float s = 0.f, s1 = 0.f, s2 = 0.f;
                for (int e = g; e < E_; e += 16) {
                    const float h = bf2f(Hw1[r * HSTR + e]) + bf2f(Hw2[r * HSTR + e]);
                    s += h * WPs[e];
                    s1 += h;
                    s2 += h * h;
                }
#pragma unroll
                for (int d = 1; d < 16; d <<= 1) {
                    s += __shfl_xor(s, d);
                    s1 += __shfl_xor(s1, d);
                    s2 += __shfl_xor(s2, d);
                }
                if (g == 0) {
                    Ps[r] = sigmoid_f(s + bp);
                    const float mu = s1 * (1.0f / (float)E_);
                    const float var = s2 * (1.0f / (float)E_) - mu * mu;
                    MUs[r] = mu;
                    RSs[r] = rsqrtf(var + 1e-5f);
                }
            }
        }
        __syncthreads();

        // ===== phase D: m update + head fixup/store =====
        if (act) {
            const float bm = BMs[eo];
#pragma unroll
            for (int j = 0; j < 4; ++j) {
                const int r = fgrp * 4 + j;
                const float pv = Ps[r];
                const float cand = tanh_f(candv[j] + bm);
                const float mold = bf2f(M1[r * HSTR + eo]) + bf2f(M2[r * HSTR + eo]);
                const float mnew = (1.0f - pv) * mold + pv * cand;
                const unsigned short m1v = f2bf(mnew);
                M1[r * HSTR + eo] = m1v;
                M2[r * HSTR + eo] = f2bf(mnew - bf2f(m1v));
            }
        }
        if (hdw && fgrp < 2 && vo < V_) {
            const float c1v = C1s[vo], c2v = C2Bs[vo];
#pragma unroll
            for (int j = 0; j < 4; ++j) {
                const int r = fgrp * 4 + j;
                const float lg = RSs[r] * (hdv[j] - MUs[r] * c1v) + c2v;
                __builtin_nontemporal_store(
                    lg, &out[((size_t)(b0 + r) * T_ + t) * V_ + vo]);
            }
        }
        __syncthreads();
    }
}

extern "C" void kernel_launch(void* const* d_in, const int* in_sizes, int n_in,
                              void* d_out, int out_size, void* d_ws, size_t ws_size,
                              hipStream_t stream) {
    const int* idx = (const int*)d_in[0];
    const float* tok = (const float*)d_in[1];
    const float* pos = (const float*)d_in[2];
    const float* w_ih = (const float*)d_in[3];
    const float* w_hh = (const float*)d_in[4];
    const float* b_ih = (const float*)d_in[5];
    const float* b_hh = (const float*)d_in[6];
    const float* w_p = (const float*)d_in[7];
    const float* b_p = (const float*)d_in[8];
    const float* w_m = (const float*)d_in[9];
    const float* b_m = (const float*)d_in[10];
    const float* ln_g = (const float*)d_in[11];
    const float* ln_b = (const float*)d_in[12];
    const float* w_head = (const float*)d_in[13];
    const float* b_head = (const float*)d_in[14];
    float* out = (float*)d_out;
    unsigned short* ws = (unsigned short*)d_ws;

    prep_weights<<<680, 256, 0, stream>>>(w_ih, w_hh, w_m, w_head, ln_g, ws);

    (void)hipFuncSetAttribute((const void*)gru_main,
                              hipFuncAttributeMaxDynamicSharedMemorySize,
                              SMEM_BYTES);
    gru_main<<<NB_, NT_, SMEM_BYTES, stream>>>(idx, tok, pos, b_ih, b_hh, w_p, b_p,
                                               b_m, ln_g, ln_b, w_head, b_head, ws, out);
}

// Round 14
// 894.223 us; speedup vs baseline: 4.6438x; 1.3421x over previous
//
#include <hip/hip_runtime.h>
#include <math.h>

// Problem constants
#define B_   2048
#define T_   256
#define E_   124
#define V_   65
#define E2_  248
#define E3_  372
#define R_   8               // batch rows per block (A-fragment rows 0-7; rows 8-15 zero)
#define NT_  512             // 8 waves
#define NB_  (B_ / R_)       // 256 blocks -> 1 per CU
#define NKC  4               // K chunks (124 padded to 128)
#define TCH  8               // timestep chunk for GX precompute

// ws offsets (unsigned shorts); frag block = 512 bf16 = 1KB — identical to R13
#define WS_WX  0                    // 24*4*512 = 49152
#define WS_WM2 49152
#define WS_HH  98304
#define WS_WM  147456               // 8*4*512
#define WS_HD  163840               // 5*4*512 (W' = ln_g ∘ w_head)
#define WS_END 174080               // shorts = 348160 B

// LDS byte offsets (16B aligned); single-bf16 state
#define HSTR 136    // row stride (shorts), 124 real + pad (pad stays 0)
#define GXSTR 376
#define L_M   0         // 8*272 = 2176
#define L_HA  2176
#define L_HB  4352
#define L_ZR  6528      // 272 B zero row (A rows 8-15)
#define L_GX  6800      // [8][8][376] shorts = 48128 -> 54928
#define L_XE  54928     // [8][8][136] shorts = 17408 -> 72336
#define L_BRZ 72336     // 248 f
#define L_BIN 73328
#define L_BHN 73824
#define L_BM  74320
#define L_WP  74816
#define L_C1  75312     // 68 f
#define L_C2B 75584     // 68 f
#define L_P   75856     // 8 f
#define L_MU  75888
#define L_RS  75920
#define L_IDX 75952     // 8*256 int = 8192
#define SMEM_BYTES 84160

typedef __attribute__((ext_vector_type(8))) short short8v;
typedef __attribute__((ext_vector_type(4))) float float4v;

__device__ __forceinline__ unsigned short f2bf(float x) {
    unsigned u = __float_as_uint(x);
    unsigned r = (u + 0x7fffu + ((u >> 16) & 1u)) >> 16;
    return (unsigned short)r;
}
__device__ __forceinline__ float bf2f(unsigned short s) {
    return __uint_as_float(((unsigned)s) << 16);
}
__device__ __forceinline__ float sigmoid_f(float x) {
    return 1.0f / (1.0f + __expf(-x));
}
__device__ __forceinline__ float tanh_f(float x) {
    return 2.0f / (1.0f + __expf(-2.0f * x)) - 1.0f;
}

// identical to R13 (validated)
__global__ void prep_weights(const float* __restrict__ w_ih,
                             const float* __restrict__ w_hh,
                             const float* __restrict__ w_m,
                             const float* __restrict__ w_head,
                             const float* __restrict__ ln_g,
                             unsigned short* __restrict__ ws) {
    for (int n = blockIdx.x * blockDim.x + threadIdx.x; n < WS_END;
         n += gridDim.x * blockDim.x) {
        const int r9 = n & 511;
        const int lane = r9 >> 3, j = r9 & 7;
        const int krel = (lane >> 4) * 8 + j;   // 0..31
        const int colrel = lane & 15;
        float w = 0.f;
        if (n < WS_WM2) {                       // WX: w_ih[:, 0:124]
            const int blk = n >> 9;
            const int c = blk & 3, tt = (blk >> 2) & 7, g = blk >> 5;
            const int k = c * 32 + krel, e = tt * 16 + colrel;
            if (k < E_ && e < E_) w = w_ih[(g * E_ + e) * E2_ + k];
        } else if (n < WS_HH) {                 // WM2: w_ih[:, 124:248]
            const int blk = (n - WS_WM2) >> 9;
            const int c = blk & 3, tt = (blk >> 2) & 7, g = blk >> 5;
            const int k = c * 32 + krel, e = tt * 16 + colrel;
            if (k < E_ && e < E_) w = w_ih[(g * E_ + e) * E2_ + E_ + k];
        } else if (n < WS_WM) {                 // HH: w_hh
            const int blk = (n - WS_HH) >> 9;
            const int c = blk & 3, tt = (blk >> 2) & 7, g = blk >> 5;
            const int k = c * 32 + krel, e = tt * 16 + colrel;
            if (k < E_ && e < E_) w = w_hh[(g * E_ + e) * E_ + k];
        } else if (n < WS_HD) {                 // WM: w_m (cand)
            const int blk = (n - WS_WM) >> 9;
            const int c = blk & 3, tt = blk >> 2;
            const int k = c * 32 + krel, e = tt * 16 + colrel;
            if (k < E_ && e < E_) w = w_m[e * E_ + k];
        } else {                                // HD: W' = ln_g ∘ w_head
            const int blk = (n - WS_HD) >> 9;
            const int c = blk & 3, tt = blk >> 2;
            const int k = c * 32 + krel, v = tt * 16 + colrel;
            if (k < E_ && v < V_) w = w_head[v * E_ + k] * ln_g[k];
        }
        ws[n] = f2bf(w);
    }
}

__global__ void __launch_bounds__(NT_, 2)
gru_main(const int* __restrict__ idx, const float* __restrict__ tok,
         const float* __restrict__ pos,
         const float* __restrict__ b_ih, const float* __restrict__ b_hh,
         const float* __restrict__ w_p, const float* __restrict__ b_p,
         const float* __restrict__ b_m,
         const float* __restrict__ ln_g, const float* __restrict__ ln_b,
         const float* __restrict__ w_head, const float* __restrict__ b_head,
         const unsigned short* __restrict__ ws, float* __restrict__ out) {
    extern __shared__ char smraw[];
    unsigned short* Ms = (unsigned short*)(smraw + L_M);
    unsigned short* ZRs = (unsigned short*)(smraw + L_ZR);
    unsigned short* GXs = (unsigned short*)(smraw + L_GX);
    unsigned short* XEs = (unsigned short*)(smraw + L_XE);
    float* BRZs = (float*)(smraw + L_BRZ);
    float* BINs = (float*)(smraw + L_BIN);
    float* BHNs = (float*)(smraw + L_BHN);
    float* BMs = (float*)(smraw + L_BM);
    float* WPs = (float*)(smraw + L_WP);
    float* C1s = (float*)(smraw + L_C1);
    float* C2Bs = (float*)(smraw + L_C2B);
    float* Ps = (float*)(smraw + L_P);
    float* MUs = (float*)(smraw + L_MU);
    float* RSs = (float*)(smraw + L_RS);
    int* IDXs = (int*)(smraw + L_IDX);

    const int tid = threadIdx.x;
    const int lane = tid & 63;
    const int wv = tid >> 6;
    const int b0 = blockIdx.x * R_;
    const int frow = lane & 15;       // A row / C col
    const int fgrp = lane >> 4;       // k-group / C row-group
    const int eo = wv * 16 + frow;    // owned e (gate/cand column)
    const bool act = (fgrp < 2) && (eo < E_);
    const bool hdw = (wv >= 2) && (wv < 7);   // head waves
    const int vo = (wv - 2) * 16 + frow;      // head output col

    // ---- one-time staging ----
    for (int i = tid; i < E2_; i += NT_) BRZs[i] = b_ih[i] + b_hh[i];
    for (int i = tid; i < E_; i += NT_) {
        BINs[i] = b_ih[E2_ + i];
        BHNs[i] = b_hh[E2_ + i];
        BMs[i] = b_m[i];
        WPs[i] = w_p[i];
    }
    for (int v = tid; v < V_; v += NT_) {       // LN-fold constants
        float s1 = 0.f, s2 = 0.f;
        for (int e = 0; e < E_; ++e) {
            const float w = w_head[v * E_ + e];
            s1 += ln_g[e] * w;
            s2 += ln_b[e] * w;
        }
        C1s[v] = s1;
        C2Bs[v] = s2 + b_head[v];
    }
    for (int i = tid; i < R_ * T_; i += NT_) IDXs[i] = idx[b0 * T_ + i];
    // zero state (M,HA,HB,ZR = 3400 shorts) and XE (8704 shorts incl. pad)
    for (int i = tid; i < 3400; i += NT_) ((unsigned short*)smraw)[i] = 0;
    for (int i = tid; i < TCH * R_ * HSTR; i += NT_) XEs[i] = 0;
    const float bp = b_p[0];

    // ---- permanent register caches: 96 VGPR (R8-proven) ----
    short8v hhf[3][NKC], wm2f[3][NKC];
#pragma unroll
    for (int g = 0; g < 3; ++g)
#pragma unroll
        for (int c = 0; c < NKC; ++c) {
            hhf[g][c]  = *(const short8v*)&ws[WS_HH  + ((g * 8 + wv) * NKC + c) * 512 + lane * 8];
            wm2f[g][c] = *(const short8v*)&ws[WS_WM2 + ((g * 8 + wv) * NKC + c) * 512 + lane * 8];
        }

    // per-lane A-operand rows (frow 0-7 = real state rows, 8-15 = zero row)
    const unsigned short* Mrow = (frow < 8) ? Ms + frow * HSTR : ZRs;
    const unsigned short* Xrow = (frow < 8) ? XEs + frow * HSTR : ZRs;
    const int xstep = (frow < 8) ? R_ * HSTR : 0;
    __syncthreads();

    float hnewv[4] = {0.f, 0.f, 0.f, 0.f};
    float candv[4] = {0.f, 0.f, 0.f, 0.f};
    float hdv[4] = {0.f, 0.f, 0.f, 0.f};

    for (int t = 0; t < T_; ++t) {
        unsigned short* Hw = (unsigned short*)(smraw + ((t & 1) ? L_HB : L_HA));
        const unsigned short* Hr = (const unsigned short*)(smraw + ((t & 1) ? L_HA : L_HB));
        const unsigned short* Hrow = (frow < 8) ? Hr + frow * HSTR : ZRs;
        const unsigned short* Hwrow = (frow < 8) ? (const unsigned short*)Hw + frow * HSTR : ZRs;

        // ===== chunk phase (every 8 steps): GX[t..t+7] = W_x @ x =====
        if ((t & 7) == 0) {
#pragma unroll
            for (int p = 0; p < 4; ++p) {
                const int i = tid + p * NT_;
                if (i < TCH * R_ * 31) {
                    const int mt = i / 248;
                    const int rem = i - mt * 248;
                    const int rr = rem / 31, q = rem - (rem / 31) * 31;
                    const int token = IDXs[rr * T_ + t + mt];
                    const int k = q * 4;
                    const float4 tv = *(const float4*)&tok[token * E_ + k];
                    const float4 pv = *(const float4*)&pos[(t + mt) * E_ + k];
#pragma unroll
                    for (int jj = 0; jj < 4; ++jj) {
                        const float x = ((const float*)&tv)[jj] + ((const float*)&pv)[jj];
                        XEs[(mt * R_ + rr) * HSTR + k + jj] = f2bf(x);
                    }
                }
            }
            __syncthreads();
#pragma unroll
            for (int g = 0; g < 3; ++g) {
                short8v bx[NKC];
#pragma unroll
                for (int c = 0; c < NKC; ++c)
                    bx[c] = *(const short8v*)&ws[WS_WX + ((g * 8 + wv) * NKC + c) * 512 + lane * 8];
                for (int mt = 0; mt < TCH; ++mt) {
                    float4v ax = (float4v){0.f, 0.f, 0.f, 0.f};
#pragma unroll
                    for (int c = 0; c < NKC; ++c) {
                        const short8v a = *(const short8v*)&Xrow[mt * xstep + c * 32 + fgrp * 8];
                        ax = __builtin_amdgcn_mfma_f32_16x16x32_bf16(a, bx[c], ax, 0, 0, 0);
                    }
                    if (act) {
#pragma unroll
                        for (int j = 0; j < 4; ++j)
                            GXs[(mt * R_ + fgrp * 4 + j) * GXSTR + g * E_ + eo] = f2bf(ax[j]);
                    }
                }
            }
            // GX consumed lane-locally (same lane wrote its own gate entries)
        }

        // ===== phase A: gi_m/gh MFMAs + in-register gates -> h_new =====
        {
            short8v am[NKC], ah[NKC];
#pragma unroll
            for (int c = 0; c < NKC; ++c) {
                am[c] = *(const short8v*)&Mrow[c * 32 + fgrp * 8];
                ah[c] = *(const short8v*)&Hrow[c * 32 + fgrp * 8];
            }
            float4v accm[3], acch[3];
#pragma unroll
            for (int g = 0; g < 3; ++g) {
                accm[g] = (float4v){0.f, 0.f, 0.f, 0.f};
                acch[g] = (float4v){0.f, 0.f, 0.f, 0.f};
            }
#pragma unroll
            for (int g = 0; g < 3; ++g)
#pragma unroll
                for (int c = 0; c < NKC; ++c) {
                    accm[g] = __builtin_amdgcn_mfma_f32_16x16x32_bf16(am[c], wm2f[g][c], accm[g], 0, 0, 0);
                    acch[g] = __builtin_amdgcn_mfma_f32_16x16x32_bf16(ah[c], hhf[g][c], acch[g], 0, 0, 0);
                }
            // rows 0-7 land directly in fgrp 0/1 lanes — no cross-lane combine
            if (act) {
                const float brz0 = BRZs[eo], brz1 = BRZs[E_ + eo];
                const float bin = BINs[eo], bhn = BHNs[eo];
                const int gxbase = ((t & 7) * R_ + fgrp * 4) * GXSTR;
#pragma unroll
                for (int j = 0; j < 4; ++j) {
                    const int r = fgrp * 4 + j;
                    const unsigned short* gxp = &GXs[gxbase + j * GXSTR];
                    const float rg = sigmoid_f(bf2f(gxp[eo]) + accm[0][j] + acch[0][j] + brz0);
                    const float z = sigmoid_f(bf2f(gxp[E_ + eo]) + accm[1][j] + acch[1][j] + brz1);
                    const float nn = tanh_f(bf2f(gxp[E2_ + eo]) + accm[2][j] + bin + rg * (acch[2][j] + bhn));
                    const float hold = bf2f(Hr[r * HSTR + eo]);
                    const float hv = (1.0f - z) * nn + z * hold;
                    hnewv[j] = hv;
                    Hw[r * HSTR + eo] = f2bf(hv);
                }
            }
        }
        __syncthreads();

        // ===== phase C: cand MFMA (all) + head MFMA (wv2-6) + wave-per-row p/LN =====
        {
            short8v ahw[NKC];
#pragma unroll
            for (int c = 0; c < NKC; ++c)
                ahw[c] = *(const short8v*)&Hwrow[c * 32 + fgrp * 8];
            float4v cc = (float4v){0.f, 0.f, 0.f, 0.f};
#pragma unroll
            for (int c = 0; c < NKC; ++c) {
                const short8v bm = *(const short8v*)&ws[WS_WM + (wv * NKC + c) * 512 + lane * 8];
                cc = __builtin_amdgcn_mfma_f32_16x16x32_bf16(ahw[c], bm, cc, 0, 0, 0);
            }
#pragma unroll
            for (int j = 0; j < 4; ++j) candv[j] = cc[j];

            if (hdw) {   // head on h_t with LN-folded weights W'
                float4v ad = (float4v){0.f, 0.f, 0.f, 0.f};
#pragma unroll
                for (int c = 0; c < NKC; ++c) {
                    const short8v bh = *(const short8v*)&ws[WS_HD + ((wv - 2) * NKC + c) * 512 + lane * 8];
                    ad = __builtin_amdgcn_mfma_f32_16x16x32_bf16(ahw[c], bh, ad, 0, 0, 0);
                }
#pragma unroll
                for (int j = 0; j < 4; ++j) hdv[j] = ad[j];
            }

            // wave wv reduces row wv: p-dot + LN stats over e (64-lane butterfly)
            {
                const float h0 = bf2f(Hw[wv * HSTR + lane]);
                const bool hi = (lane < E_ - 64);
                const float h1v = hi ? bf2f(Hw[wv * HSTR + 64 + lane]) : 0.f;
                float s = h0 * WPs[lane] + (hi ? h1v * WPs[64 + lane] : 0.f);
                float s1 = h0 + h1v;
                float s2 = h0 * h0 + h1v * h1v;
#pragma unroll
                for (int d = 1; d < 64; d <<= 1) {
                    s += __shfl_xor(s, d);
                    s1 += __shfl_xor(s1, d);
                    s2 += __shfl_xor(s2, d);
                }
                if (lane == 0) {
                    Ps[wv] = sigmoid_f(s + bp);
                    const float mu = s1 * (1.0f / (float)E_);
                    const float var = s2 * (1.0f / (float)E_) - mu * mu;
                    MUs[wv] = mu;
                    RSs[wv] = rsqrtf(var + 1e-5f);
                }
            }
        }
        __syncthreads();

        // ===== phase D: m update + head fixup/store =====
        if (act) {
            const float bm = BMs[eo];
#pragma unroll
            for (int j = 0; j < 4; ++j) {
                const int r = fgrp * 4 + j;
                const float pv = Ps[r];
                const float cand = tanh_f(candv[j] + bm);
                const float mold = bf2f(Ms[r * HSTR + eo]);
                const float mnew = (1.0f - pv) * mold + pv * cand;
                Ms[r * HSTR + eo] = f2bf(mnew);
            }
        }
        if (hdw && fgrp < 2 && vo < V_) {
            const float c1v = C1s[vo], c2v = C2Bs[vo];
#pragma unroll
            for (int j = 0; j < 4; ++j) {
                const int r = fgrp * 4 + j;
                const float lg = RSs[r] * (hdv[j] - MUs[r] * c1v) + c2v;
                __builtin_nontemporal_store(
                    lg, &out[((size_t)(b0 + r) * T_ + t) * V_ + vo]);
            }
        }
        __syncthreads();
    }
}

extern "C" void kernel_launch(void* const* d_in, const int* in_sizes, int n_in,
                              void* d_out, int out_size, void* d_ws, size_t ws_size,
                              hipStream_t stream) {
    const int* idx = (const int*)d_in[0];
    const float* tok = (const float*)d_in[1];
    const float* pos = (const float*)d_in[2];
    const float* w_ih = (const float*)d_in[3];
    const float* w_hh = (const float*)d_in[4];
    const float* b_ih = (const float*)d_in[5];
    const float* b_hh = (const float*)d_in[6];
    const float* w_p = (const float*)d_in[7];
    const float* b_p = (const float*)d_in[8];
    const float* w_m = (const float*)d_in[9];
    const float* b_m = (const float*)d_in[10];
    const float* ln_g = (const float*)d_in[11];
    const float* ln_b = (const float*)d_in[12];
    const float* w_head = (const float*)d_in[13];
    const float* b_head = (const float*)d_in[14];
    float* out = (float*)d_out;
    unsigned short* ws = (unsigned short*)d_ws;

    prep_weights<<<680, 256, 0, stream>>>(w_ih, w_hh, w_m, w_head, ln_g, ws);

    (void)hipFuncSetAttribute((const void*)gru_main,
                              hipFuncAttributeMaxDynamicSharedMemorySize,
                              SMEM_BYTES);
    gru_main<<<NB_, NT_, SMEM_BYTES, stream>>>(idx, tok, pos, b_ih, b_hh, w_p, b_p,
                                               b_m, ln_g, ln_b, w_head, b_head, ws, out);
}